// Round 9
// baseline (340.765 us; speedup 1.0000x reference)
//
#include <hip/hip_runtime.h>

#define NN 50000
#define NE 150000
#define CAP 32   // max bucket slots; degrees are Poisson(3), P(deg>=32) ~ 1e-20
#define REPS 4   // in-kernel amplification: rep 0 real, reps 1..3 -> dummy outputs

// ---------- K1: degree-count + bucket scatter (amplified x4) ----------
__global__ __launch_bounds__(256) void k_scat(const int* __restrict__ src,
                                              const int* __restrict__ dst,
                                              int* cnt_in, int* cnt_out,
                                              int2* pbuck, int* obuck,
                                              int* cnt_in_d, int* cnt_out_d,
                                              int2* pbuck_d, int* obuck_d, size_t z) {
    int e = blockIdx.x * 256 + threadIdx.x;
    if (e >= NE) return;
    #pragma unroll 1
    for (int r = 0; r < REPS; r++) {
        const int* S = src + z * r;   // z==0 at runtime; defeats cross-rep CSE
        const int* D = dst + z * r;
        int*  ci = r ? cnt_in_d  + (r - 1) * NN : cnt_in;
        int*  co = r ? cnt_out_d + (r - 1) * NN : cnt_out;
        int2* pb = r ? pbuck_d + (size_t)(r - 1) * NN * CAP : pbuck;
        int*  ob = r ? obuck_d + (size_t)(r - 1) * NN * CAP : obuck;
        int s = S[e], d = D[e];
        int si = atomicAdd(&ci[d], 1) & (CAP - 1);   // dummy cnt garbage-init: masked, safe
        pb[(size_t)d * CAP + si] = make_int2(e, s);
        int so = atomicAdd(&co[s], 1) & (CAP - 1);
        ob[(size_t)s * CAP + so] = d;
    }
}

// ---------- K2: node precompute (amplified x4) ----------
__global__ __launch_bounds__(256) void k_node(const float* __restrict__ x,
                                              const int* __restrict__ cnt_in,
                                              const int* __restrict__ cnt_out,
                                              float* din_arr, float4* dsx4,
                                              float* din_d, float4* dsx4_d, size_t z) {
    int n = blockIdx.x * 256 + threadIdx.x;
    if (n >= NN) return;
    #pragma unroll 1
    for (int r = 0; r < REPS; r++) {
        const int* CI = cnt_in + z * r;
        const int* CO = cnt_out + z * r;
        const float* X = x + z * r;
        float*  dn = r ? din_d  + (r - 1) * NN : din_arr;
        float4* dx = r ? dsx4_d + (r - 1) * NN : dsx4;
        dn[n] = rsqrtf((float)(CI[n] + 1));
        float dout = rsqrtf((float)(CO[n] + 1));
        float4 xv = ((const float4*)X)[n];
        xv.x *= dout; xv.y *= dout; xv.z *= dout; xv.w *= dout;
        dx[n] = xv;
    }
}

// ---------- K3: conv1 gather (amplified x4) ----------
__global__ __launch_bounds__(256) void k_conv1c(const int* __restrict__ cnt_in,
                                                const int* __restrict__ cnt_out,
                                                const int2* __restrict__ pbuck,
                                                const int* __restrict__ obuck,
                                                const float* __restrict__ din_arr,
                                                const float4* __restrict__ dsx4,
                                                const float* __restrict__ W1,
                                                const float* __restrict__ b1,
                                                float* h1s, float* c,
                                                float* h1s_d, float* c_d, size_t z) {
    int tid = threadIdx.x;
    int n = blockIdx.x * 64 + (tid >> 2);
    int sub = tid & 3;
    if (n >= NN) return;
    int ci = cnt_in[n], co = cnt_out[n];
    float din  = rsqrtf((float)(ci + 1));
    float dout = rsqrtf((float)(co + 1));
    #pragma unroll 1
    for (int r = 0; r < REPS; r++) {
        const int2*   PB = pbuck   + z * r;
        const int*    OB = obuck   + z * r;
        const float4* DX = dsx4    + z * r;
        const float*  DN = din_arr + z * r;
        float* H = r ? h1s_d + (size_t)(r - 1) * NN * 11 : h1s;
        float* C = r ? c_d + (r - 1) * NN : c;
        float a0 = 0.f, a1 = 0.f, a2 = 0.f, a3 = 0.f;
        const int2* pb = PB + (size_t)n * CAP;
        for (int i = sub; i < ci; i += 4) {
            int2 p = pb[i];
            float4 u = DX[p.y];
            a0 += u.x; a1 += u.y; a2 += u.z; a3 += u.w;
        }
        float cacc = 0.f;
        const int* ob = OB + (size_t)n * CAP;
        for (int i = sub; i < co; i += 4) cacc += DN[ob[i]];
        #pragma unroll
        for (int m = 1; m < 4; m <<= 1) {
            a0 += __shfl_xor(a0, m); a1 += __shfl_xor(a1, m);
            a2 += __shfl_xor(a2, m); a3 += __shfl_xor(a3, m);
            cacc += __shfl_xor(cacc, m);
        }
        float4 sv = DX[n];
        a0 += sv.x; a1 += sv.y; a2 += sv.z; a3 += sv.w;
        if (sub == 0) C[n] = cacc + din;
        #pragma unroll
        for (int jj = 0; jj < 3; jj++) {
            int j = sub + 4 * jj;
            if (j < 11) {
                float y = a0 * W1[0 * 11 + j] + a1 * W1[1 * 11 + j] +
                          a2 * W1[2 * 11 + j] + a3 * W1[3 * 11 + j];
                y = fmaxf(fmaf(y, din, b1[j]), 0.f);
                H[(size_t)n * 11 + j] = y * dout;
            }
        }
    }
}

// ---------- K4: conv2 aggregation (amplified x4) ----------
__global__ __launch_bounds__(256) void k_agg2(const int* __restrict__ cnt_in,
                                              const int2* __restrict__ pbuck,
                                              const float* __restrict__ h1s,
                                              const float* __restrict__ ef,
                                              float* agg2, float* agg2_d, size_t z) {
    int tid = threadIdx.x;
    if (tid >= 253) return;
    int q = tid / 11;
    int n = blockIdx.x * 23 + q;
    int j = tid - q * 11;
    if (n >= NN) return;
    int ci = cnt_in[n];
    #pragma unroll 1
    for (int r = 0; r < REPS; r++) {
        const int2*  PB = pbuck + z * r;
        const float* H  = h1s + z * r;
        const float* EF = ef + z * r;
        float* A = r ? agg2_d + (size_t)(r - 1) * NN * 11 : agg2;
        const int2* pb = PB + (size_t)n * CAP;
        float acc = 0.f;
        for (int i = 0; i < ci; i++) {
            int2 p = pb[i];
            acc = fmaf(H[(size_t)p.y * 11 + j], EF[(size_t)p.x * 11 + j], acc);
        }
        A[(size_t)n * 11 + j] = acc;
    }
}

// ---------- K5: conv2 matvec + weighted-mean reduce (amplified x4) ----------
#define NPB 64
__global__ __launch_bounds__(512) void k_conv2_reduce(const float* __restrict__ agg2,
                                                      const float* __restrict__ W2,
                                                      const float* __restrict__ b2,
                                                      const float* __restrict__ c,
                                                      const int* __restrict__ cnt_out,
                                                      const int* __restrict__ cnt_in,
                                                      float* t, float* t_d, size_t z) {
    __shared__ float tile[NPB * 11];
    __shared__ float din_sh[NPB], w_sh[NPB];
    int n0 = blockIdx.x * NPB;
    int tid = threadIdx.x;
    #pragma unroll 1
    for (int r = 0; r < REPS; r++) {
        const float* A = agg2 + z * r;
        const float* CC = c + z * r;
        float* T = r ? t_d + (r - 1) * 512 : t;
        __syncthreads();
        for (int i = tid; i < NPB * 11; i += 512) {
            int gi = n0 * 11 + i;
            tile[i] = (gi < NN * 11) ? A[gi] : 0.f;
        }
        if (tid < NPB) {
            int node = n0 + tid;
            if (node < NN) {
                din_sh[tid] = rsqrtf((float)(cnt_in[node] + 1));
                w_sh[tid]   = CC[node] * rsqrtf((float)(cnt_out[node] + 1)) * (1.0f / NN);
            } else { din_sh[tid] = 0.f; w_sh[tid] = 0.f; }
        }
        __syncthreads();
        float w[11];
        #pragma unroll
        for (int j = 0; j < 11; j++) w[j] = W2[j * 512 + tid];
        float bias = b2[tid];
        float acc = 0.f;
        for (int i = 0; i < NPB; i++) {
            float dot = 0.f;
            #pragma unroll
            for (int j = 0; j < 11; j++) dot = fmaf(tile[i * 11 + j], w[j], dot);
            float y = fmaxf(fmaf(dot, din_sh[i], bias), 0.f);
            acc = fmaf(w_sh[i], y, acc);
        }
        atomicAdd(&T[tid], acc);
    }
}

// ---------- K6: g = t @ W3 + b3 (amplified x4) ----------
__global__ __launch_bounds__(256) void k_g(const float* __restrict__ t,
                                           const float* __restrict__ W3,
                                           const float* __restrict__ b3,
                                           float* g, float* g_d, size_t z) {
    int b = blockIdx.x;
    int oc = b & 3, kc = b >> 2;
    int o = oc * 256 + threadIdx.x;
    int k0 = kc * 32;
    __shared__ float ts[32];
    #pragma unroll 1
    for (int r = 0; r < REPS; r++) {
        const float* T = t + z * r;
        const float* W = W3 + z * r;
        float* G = r ? g_d + (r - 1) * 1024 : g;
        __syncthreads();
        if (threadIdx.x < 32) ts[threadIdx.x] = T[k0 + threadIdx.x];
        __syncthreads();
        float acc = (kc == 0) ? b3[o] : 0.f;
        #pragma unroll 8
        for (int k = 0; k < 32; k++)
            acc = fmaf(ts[k], W[(size_t)(k0 + k) * 1024 + o], acc);
        atomicAdd(&G[o], acc);
    }
}

// ---------- K7: head layer-1 partials (amplified x4) ----------
__global__ __launch_bounds__(256) void k_heads1(const float* __restrict__ g,
                                                const float* __restrict__ Wv1,
                                                const float* __restrict__ Wa1,
                                                float* hv_raw, float* ha_raw,
                                                float* hv_d, float* ha_d, size_t z) {
    int b = blockIdx.x;
    int oc = b >> 4, kc = b & 15;
    int idx = oc * 256 + threadIdx.x;  // 0..4095
    int k0 = kc * 64;
    __shared__ float gs[64];
    #pragma unroll 1
    for (int r = 0; r < REPS; r++) {
        const float* G = g + z * r;
        __syncthreads();
        if (threadIdx.x < 64) gs[threadIdx.x] = G[k0 + threadIdx.x];
        __syncthreads();
        const float* W; float* outp; int o;
        if (idx < 2048) {
            W = Wv1 + z * r;
            outp = r ? hv_d + (r - 1) * 2048 : hv_raw;
            o = idx;
        } else {
            W = Wa1 + z * r;
            outp = r ? ha_d + (r - 1) * 2048 : ha_raw;
            o = idx - 2048;
        }
        float acc = 0.f;
        #pragma unroll 8
        for (int k = 0; k < 64; k++)
            acc = fmaf(gs[k], W[(size_t)(k0 + k) * 2048 + o], acc);
        atomicAdd(&outp[o], acc);
    }
}

// ---------- K8: head layer-2 + fused final (NOT amplified; exit-style lastFlag) ----------
__global__ __launch_bounds__(256) void k_heads2f(const float* __restrict__ hv_raw,
                                                 const float* __restrict__ bv1,
                                                 const float* __restrict__ ha_raw,
                                                 const float* __restrict__ ba1,
                                                 const float* __restrict__ Wv2,
                                                 const float* __restrict__ bv2,
                                                 const float* __restrict__ Wa2,
                                                 const float* __restrict__ ba2,
                                                 float* __restrict__ a_acc,
                                                 float* __restrict__ v,
                                                 int* __restrict__ done,
                                                 float* __restrict__ out) {
    __shared__ float sh[256];
    __shared__ int lastFlag;
    int b = blockIdx.x;
    int tid = threadIdx.x;
    if (b < 128) {
        int oc = b >> 5, kc = b & 31;
        int k0 = kc * 64;
        if (tid < 64) sh[tid] = fmaxf(ha_raw[k0 + tid] + ba1[k0 + tid], 0.f);
        __syncthreads();
        int o = oc * 256 + tid;
        if (o < 1000) {
            float acc = 0.f;
            #pragma unroll 8
            for (int k = 0; k < 64; k++)
                acc = fmaf(sh[k], Wa2[(size_t)(k0 + k) * 1000 + o], acc);
            atomicAdd(&a_acc[o], acc);
        }
    } else {
        float acc = 0.f;
        for (int k = tid; k < 2048; k += 256)
            acc = fmaf(fmaxf(hv_raw[k] + bv1[k], 0.f), Wv2[k], acc);
        sh[tid] = acc;
        __syncthreads();
        for (int s2 = 128; s2 >= 1; s2 >>= 1) {
            if (tid < s2) sh[tid] += sh[tid + s2];
            __syncthreads();
        }
        if (tid == 0) *v = sh[0] + bv2[0];
    }
    __syncthreads();
    if (tid == 0) {
        __threadfence();
        int old = atomicAdd(done, 1);
        lastFlag = (old == 128) ? 1 : 0;
    }
    __syncthreads();
    if (!lastFlag) return;
    __threadfence();
    float ai[4];
    float lsum = 0.f;
    #pragma unroll
    for (int k = 0; k < 4; k++) {
        int idx = tid + k * 256;
        float val = (idx < 1000) ? a_acc[idx] + ba2[idx] : 0.f;
        ai[k] = val;
        lsum += val;
    }
    __syncthreads();
    sh[tid] = lsum;
    __syncthreads();
    for (int s2 = 128; s2 >= 1; s2 >>= 1) {
        if (tid < s2) sh[tid] += sh[tid + s2];
        __syncthreads();
    }
    float amean = sh[0] * (1.0f / 1000.0f);
    float vv = *v;
    #pragma unroll
    for (int k = 0; k < 4; k++) {
        int idx = tid + k * 256;
        if (idx < 1000) out[idx] = vv + ai[k] - amean;
    }
}

extern "C" void kernel_launch(void* const* d_in, const int* in_sizes, int n_in,
                              void* d_out, int out_size, void* d_ws, size_t ws_size,
                              hipStream_t stream) {
    const float* x   = (const float*)d_in[0];
    const float* ef  = (const float*)d_in[1];
    const float* W1  = (const float*)d_in[2];
    const float* b1  = (const float*)d_in[3];
    const float* W2  = (const float*)d_in[4];
    const float* b2  = (const float*)d_in[5];
    const float* W3  = (const float*)d_in[6];
    const float* b3  = (const float*)d_in[7];
    const float* Wv1 = (const float*)d_in[8];
    const float* bv1 = (const float*)d_in[9];
    const float* Wv2 = (const float*)d_in[10];
    const float* bv2 = (const float*)d_in[11];
    const float* Wa1 = (const float*)d_in[12];
    const float* ba1 = (const float*)d_in[13];
    const float* Wa2 = (const float*)d_in[14];
    const float* ba2 = (const float*)d_in[15];
    const int*   src = (const int*)d_in[16];
    const int*   dst = (const int*)d_in[17];
    float* out = (float*)d_out;

    char* ws = (char*)d_ws;
    size_t off = 0;
    auto alloc = [&](size_t bytes) -> void* {
        void* p = ws + off;
        off = (off + bytes + 255) & ~(size_t)255;
        return p;
    };
    // --- zeroed region (real counters + accumulators only) ---
    int*   cnt_in  = (int*)  alloc(NN * 4);
    int*   cnt_out = (int*)  alloc(NN * 4);
    float* t       = (float*)alloc(512 * 4);
    float* g       = (float*)alloc(1024 * 4);
    float* hv_raw  = (float*)alloc(2048 * 4);
    float* ha_raw  = (float*)alloc(2048 * 4);
    float* a_acc   = (float*)alloc(1024 * 4);
    int*   done    = (int*)  alloc(256);
    size_t zero_bytes = off;
    // --- non-zeroed real scratch ---
    int2*  pbuck   = (int2*) alloc((size_t)NN * CAP * 8);
    int*   obuck   = (int*)  alloc((size_t)NN * CAP * 4);
    float* din_arr = (float*)alloc(NN * 4);
    float4* dsx4   = (float4*)alloc((size_t)NN * 16);
    float* c       = (float*)alloc(NN * 4);
    float* h1s     = (float*)alloc((size_t)NN * 11 * 4);
    float* agg2    = (float*)alloc((size_t)NN * 11 * 4);
    float* v       = (float*)alloc(256);
    // --- dummy amplification sinks (3 reps each; garbage-init is fine) ---
    int*   cnt_in_d  = (int*)  alloc((size_t)3 * NN * 4);
    int*   cnt_out_d = (int*)  alloc((size_t)3 * NN * 4);
    int2*  pbuck_d   = (int2*) alloc((size_t)3 * NN * CAP * 8);
    int*   obuck_d   = (int*)  alloc((size_t)3 * NN * CAP * 4);
    float* din_d     = (float*)alloc((size_t)3 * NN * 4);
    float4* dsx4_d   = (float4*)alloc((size_t)3 * NN * 16);
    float* h1s_d     = (float*)alloc((size_t)3 * NN * 11 * 4);
    float* c_d       = (float*)alloc((size_t)3 * NN * 4);
    float* agg2_d    = (float*)alloc((size_t)3 * NN * 11 * 4);
    float* t_d       = (float*)alloc((size_t)3 * 512 * 4);
    float* g_d       = (float*)alloc((size_t)3 * 1024 * 4);
    float* hv_d      = (float*)alloc((size_t)3 * 2048 * 4);
    float* ha_d      = (float*)alloc((size_t)3 * 2048 * 4);

    const size_t Z = 0;   // runtime-zero offset: opaque to compiler, defeats CSE

    hipMemsetAsync(d_ws, 0, zero_bytes, stream);

    k_scat<<<(NE + 255) / 256, 256, 0, stream>>>(src, dst, cnt_in, cnt_out, pbuck, obuck,
                                                 cnt_in_d, cnt_out_d, pbuck_d, obuck_d, Z);
    k_node<<<(NN + 255) / 256, 256, 0, stream>>>(x, cnt_in, cnt_out, din_arr, dsx4,
                                                 din_d, dsx4_d, Z);
    k_conv1c<<<(NN + 63) / 64, 256, 0, stream>>>(cnt_in, cnt_out, pbuck, obuck,
                                                 din_arr, dsx4, W1, b1, h1s, c,
                                                 h1s_d, c_d, Z);
    k_agg2<<<(NN + 22) / 23, 256, 0, stream>>>(cnt_in, pbuck, h1s, ef, agg2, agg2_d, Z);
    k_conv2_reduce<<<(NN + NPB - 1) / NPB, 512, 0, stream>>>(agg2, W2, b2, c,
                                                             cnt_out, cnt_in, t, t_d, Z);
    k_g<<<64, 256, 0, stream>>>(t, W3, b3, g, g_d, Z);
    k_heads1<<<256, 256, 0, stream>>>(g, Wv1, Wa1, hv_raw, ha_raw, hv_d, ha_d, Z);
    k_heads2f<<<129, 256, 0, stream>>>(hv_raw, bv1, ha_raw, ba1, Wv2, bv2, Wa2, ba2,
                                       a_acc, v, done, out);
}

// Round 10
// 185.143 us; speedup vs baseline: 1.8405x; 1.8405x over previous
//
#include <hip/hip_runtime.h>

#define NN 50000
#define NE 150000
#define CAP 32   // max bucket slots; degrees are Poisson(3), P(deg>=32) ~ 1e-20

// ---------- K1: fused degree-count + bucket scatter ----------
// Atomic/line-service-rate bound (~20-26us measured via x4 amplification, R9).
// Payload shrink does NOT help: dirty lines ~= 1/node is the floor.
__global__ __launch_bounds__(256) void k_scat(const int* __restrict__ src,
                                              const int* __restrict__ dst,
                                              int* __restrict__ cnt_in,
                                              int* __restrict__ cnt_out,
                                              int2* __restrict__ pbuck,
                                              int* __restrict__ obuck) {
    int e = blockIdx.x * 256 + threadIdx.x;
    if (e >= NE) return;
    int s = src[e], d = dst[e];
    int si = atomicAdd(&cnt_in[d], 1) & (CAP - 1);
    pbuck[(size_t)d * CAP + si] = make_int2(e, s);
    int so = atomicAdd(&cnt_out[s], 1) & (CAP - 1);
    obuck[(size_t)s * CAP + so] = d;
}

// ---------- K2: per-node precompute: din table + pre-scaled features ----------
// Prescale (dsx4) is load-bearing: computing scales on the fly in conv1 costs
// +1 dependent load per edge and regressed 185->200 (R4).
__global__ __launch_bounds__(256) void k_node(const float* __restrict__ x,
                                              const int* __restrict__ cnt_in,
                                              const int* __restrict__ cnt_out,
                                              float* __restrict__ din_arr,
                                              float4* __restrict__ dsx4) {
    int n = blockIdx.x * 256 + threadIdx.x;
    if (n >= NN) return;
    din_arr[n] = rsqrtf((float)(cnt_in[n] + 1));
    float dout = rsqrtf((float)(cnt_out[n] + 1));
    float4 xv = ((const float4*)x)[n];
    xv.x *= dout; xv.y *= dout; xv.z *= dout; xv.w *= dout;
    dsx4[n] = xv;
}

// ---------- K3: conv1 gather (4 lanes/node) + c gather + 4->11 matvec/relu ----------
__global__ __launch_bounds__(256) void k_conv1c(const int* __restrict__ cnt_in,
                                                const int* __restrict__ cnt_out,
                                                const int2* __restrict__ pbuck,
                                                const int* __restrict__ obuck,
                                                const float* __restrict__ din_arr,
                                                const float4* __restrict__ dsx4,
                                                const float* __restrict__ W1,
                                                const float* __restrict__ b1,
                                                float* __restrict__ h1s,
                                                float* __restrict__ c) {
    int tid = threadIdx.x;
    int n = blockIdx.x * 64 + (tid >> 2);
    int sub = tid & 3;
    if (n >= NN) return;
    int ci = cnt_in[n], co = cnt_out[n];
    float din  = rsqrtf((float)(ci + 1));
    float dout = rsqrtf((float)(co + 1));
    float a0 = 0.f, a1 = 0.f, a2 = 0.f, a3 = 0.f;
    const int2* pb = pbuck + (size_t)n * CAP;
    for (int i = sub; i < ci; i += 4) {
        int2 p = pb[i];                  // (e, s); only s needed here
        float4 u = dsx4[p.y];
        a0 += u.x; a1 += u.y; a2 += u.z; a3 += u.w;
    }
    float cacc = 0.f;
    const int* ob = obuck + (size_t)n * CAP;
    for (int i = sub; i < co; i += 4) cacc += din_arr[ob[i]];
    // reduce across the 4-lane group
    #pragma unroll
    for (int m = 1; m < 4; m <<= 1) {
        a0 += __shfl_xor(a0, m); a1 += __shfl_xor(a1, m);
        a2 += __shfl_xor(a2, m); a3 += __shfl_xor(a3, m);
        cacc += __shfl_xor(cacc, m);
    }
    float4 sv = dsx4[n];                 // self-loop term (already dout-scaled)
    a0 += sv.x; a1 += sv.y; a2 += sv.z; a3 += sv.w;
    if (sub == 0) c[n] = cacc + din;     // self-loop contributes din
    #pragma unroll
    for (int jj = 0; jj < 3; jj++) {
        int j = sub + 4 * jj;
        if (j < 11) {
            float y = a0 * W1[0 * 11 + j] + a1 * W1[1 * 11 + j] +
                      a2 * W1[2 * 11 + j] + a3 * W1[3 * 11 + j];
            y = fmaxf(fmaf(y, din, b1[j]), 0.f);
            h1s[n * 11 + j] = y * dout;
        }
    }
}

// ---------- K4: conv2 aggregation via pair-bucket gather (self loops ef=0 -> skip) ----------
__global__ __launch_bounds__(256) void k_agg2(const int* __restrict__ cnt_in,
                                              const int2* __restrict__ pbuck,
                                              const float* __restrict__ h1s,
                                              const float* __restrict__ ef,
                                              float* __restrict__ agg2) {
    int tid = threadIdx.x;
    if (tid >= 253) return;
    int q = tid / 11;
    int n = blockIdx.x * 23 + q;
    int j = tid - q * 11;
    if (n >= NN) return;
    int ci = cnt_in[n];
    const int2* pb = pbuck + (size_t)n * CAP;
    float acc = 0.f;
    for (int i = 0; i < ci; i++) {
        int2 p = pb[i];                  // (e, s)
        acc = fmaf(h1s[(size_t)p.y * 11 + j], ef[(size_t)p.x * 11 + j], acc);
    }
    agg2[(size_t)n * 11 + j] = acc;
}

// ---------- K5: conv2 matvec+relu fused with weighted mean-reduction into t[512] ----------
// t atomics (782 adds/address) measured cheap (R2 vs R4: atomic-free partials were SLOWER).
#define NPB 64
__global__ __launch_bounds__(512) void k_conv2_reduce(const float* __restrict__ agg2,
                                                      const float* __restrict__ W2,
                                                      const float* __restrict__ b2,
                                                      const float* __restrict__ c,
                                                      const int* __restrict__ deg_out,
                                                      const int* __restrict__ deg_in,
                                                      float* __restrict__ t) {
    __shared__ float tile[NPB * 11];
    __shared__ float din_sh[NPB], w_sh[NPB];
    int n0 = blockIdx.x * NPB;
    int tid = threadIdx.x;
    for (int i = tid; i < NPB * 11; i += 512) {
        int gi = n0 * 11 + i;
        tile[i] = (gi < NN * 11) ? agg2[gi] : 0.f;
    }
    if (tid < NPB) {
        int node = n0 + tid;
        if (node < NN) {
            din_sh[tid] = rsqrtf((float)(deg_in[node] + 1));
            w_sh[tid]   = c[node] * rsqrtf((float)(deg_out[node] + 1)) * (1.0f / NN);
        } else { din_sh[tid] = 0.f; w_sh[tid] = 0.f; }
    }
    __syncthreads();
    float w[11];
    #pragma unroll
    for (int j = 0; j < 11; j++) w[j] = W2[j * 512 + tid];
    float bias = b2[tid];
    float acc = 0.f;
    for (int i = 0; i < NPB; i++) {
        float dot = 0.f;
        #pragma unroll
        for (int j = 0; j < 11; j++) dot = fmaf(tile[i * 11 + j], w[j], dot);
        float y = fmaxf(fmaf(dot, din_sh[i], bias), 0.f);
        acc = fmaf(w_sh[i], y, acc);
    }
    atomicAdd(&t[tid], acc);
}

// ---------- K6: g = t @ W3 + b3  (512x1024 matvec, k-split 16 ways) ----------
__global__ __launch_bounds__(256) void k_g(const float* __restrict__ t,
                                           const float* __restrict__ W3,
                                           const float* __restrict__ b3,
                                           float* __restrict__ g) {
    int b = blockIdx.x;          // 64 = 4 oc x 16 kc
    int oc = b & 3, kc = b >> 2;
    int o = oc * 256 + threadIdx.x;
    int k0 = kc * 32;
    __shared__ float ts[32];
    if (threadIdx.x < 32) ts[threadIdx.x] = t[k0 + threadIdx.x];
    __syncthreads();
    float acc = (kc == 0) ? b3[o] : 0.f;
    #pragma unroll 8
    for (int k = 0; k < 32; k++) acc = fmaf(ts[k], W3[(size_t)(k0 + k) * 1024 + o], acc);
    atomicAdd(&g[o], acc);
}

// ---------- K7: head layer-1 partial matvecs (bias/relu deferred) ----------
__global__ __launch_bounds__(256) void k_heads1(const float* __restrict__ g,
                                                const float* __restrict__ Wv1,
                                                const float* __restrict__ Wa1,
                                                float* __restrict__ hv_raw,
                                                float* __restrict__ ha_raw) {
    int b = blockIdx.x;
    int oc = b >> 4, kc = b & 15;
    int idx = oc * 256 + threadIdx.x;  // 0..4095
    int k0 = kc * 64;
    __shared__ float gs[64];
    if (threadIdx.x < 64) gs[threadIdx.x] = g[k0 + threadIdx.x];
    __syncthreads();
    const float* W; float* outp; int o;
    if (idx < 2048) { W = Wv1; outp = hv_raw; o = idx; }
    else            { W = Wa1; outp = ha_raw; o = idx - 2048; }
    float acc = 0.f;
    #pragma unroll 8
    for (int k = 0; k < 64; k++) acc = fmaf(gs[k], W[(size_t)(k0 + k) * 2048 + o], acc);
    atomicAdd(&outp[o], acc);
}

// ---------- K8: head layer-2 + fused final (exit-style lastFlag; no spinning) ----------
__global__ __launch_bounds__(256) void k_heads2f(const float* __restrict__ hv_raw,
                                                 const float* __restrict__ bv1,
                                                 const float* __restrict__ ha_raw,
                                                 const float* __restrict__ ba1,
                                                 const float* __restrict__ Wv2,
                                                 const float* __restrict__ bv2,
                                                 const float* __restrict__ Wa2,
                                                 const float* __restrict__ ba2,
                                                 float* __restrict__ a_acc,
                                                 float* __restrict__ v,
                                                 int* __restrict__ done,
                                                 float* __restrict__ out) {
    __shared__ float sh[256];
    __shared__ int lastFlag;
    int b = blockIdx.x;
    int tid = threadIdx.x;
    if (b < 128) {
        int oc = b >> 5, kc = b & 31;   // oc 0..3, kc 0..31
        int k0 = kc * 64;
        if (tid < 64) sh[tid] = fmaxf(ha_raw[k0 + tid] + ba1[k0 + tid], 0.f);
        __syncthreads();
        int o = oc * 256 + tid;  // 0..1023
        if (o < 1000) {
            float acc = 0.f;
            #pragma unroll 8
            for (int k = 0; k < 64; k++)
                acc = fmaf(sh[k], Wa2[(size_t)(k0 + k) * 1000 + o], acc);
            atomicAdd(&a_acc[o], acc);
        }
    } else {
        float acc = 0.f;
        for (int k = tid; k < 2048; k += 256)
            acc = fmaf(fmaxf(hv_raw[k] + bv1[k], 0.f), Wv2[k], acc);
        sh[tid] = acc;
        __syncthreads();
        for (int s2 = 128; s2 >= 1; s2 >>= 1) {
            if (tid < s2) sh[tid] += sh[tid + s2];
            __syncthreads();
        }
        if (tid == 0) *v = sh[0] + bv2[0];
    }
    __syncthreads();
    if (tid == 0) {
        __threadfence();
        int old = atomicAdd(done, 1);
        lastFlag = (old == 128) ? 1 : 0;
    }
    __syncthreads();
    if (!lastFlag) return;
    __threadfence();
    float ai[4];
    float lsum = 0.f;
    #pragma unroll
    for (int k = 0; k < 4; k++) {
        int idx = tid + k * 256;
        float val = (idx < 1000) ? a_acc[idx] + ba2[idx] : 0.f;
        ai[k] = val;
        lsum += val;
    }
    __syncthreads();
    sh[tid] = lsum;
    __syncthreads();
    for (int s2 = 128; s2 >= 1; s2 >>= 1) {
        if (tid < s2) sh[tid] += sh[tid + s2];
        __syncthreads();
    }
    float amean = sh[0] * (1.0f / 1000.0f);
    float vv = *v;
    #pragma unroll
    for (int k = 0; k < 4; k++) {
        int idx = tid + k * 256;
        if (idx < 1000) out[idx] = vv + ai[k] - amean;
    }
}

extern "C" void kernel_launch(void* const* d_in, const int* in_sizes, int n_in,
                              void* d_out, int out_size, void* d_ws, size_t ws_size,
                              hipStream_t stream) {
    const float* x   = (const float*)d_in[0];
    const float* ef  = (const float*)d_in[1];
    const float* W1  = (const float*)d_in[2];
    const float* b1  = (const float*)d_in[3];
    const float* W2  = (const float*)d_in[4];
    const float* b2  = (const float*)d_in[5];
    const float* W3  = (const float*)d_in[6];
    const float* b3  = (const float*)d_in[7];
    const float* Wv1 = (const float*)d_in[8];
    const float* bv1 = (const float*)d_in[9];
    const float* Wv2 = (const float*)d_in[10];
    const float* bv2 = (const float*)d_in[11];
    const float* Wa1 = (const float*)d_in[12];
    const float* ba1 = (const float*)d_in[13];
    const float* Wa2 = (const float*)d_in[14];
    const float* ba2 = (const float*)d_in[15];
    const int*   src = (const int*)d_in[16];
    const int*   dst = (const int*)d_in[17];
    float* out = (float*)d_out;

    char* ws = (char*)d_ws;
    size_t off = 0;
    auto alloc = [&](size_t bytes) -> void* {
        void* p = ws + off;
        off = (off + bytes + 255) & ~(size_t)255;
        return p;
    };
    // --- zeroed region (counters + accumulators) ---
    int*   cnt_in  = (int*)  alloc(NN * 4);
    int*   cnt_out = (int*)  alloc(NN * 4);
    float* t       = (float*)alloc(512 * 4);
    float* g       = (float*)alloc(1024 * 4);
    float* hv_raw  = (float*)alloc(2048 * 4);
    float* ha_raw  = (float*)alloc(2048 * 4);
    float* a_acc   = (float*)alloc(1024 * 4);
    int*   done    = (int*)  alloc(256);
    size_t zero_bytes = off;
    // --- non-zeroed scratch ---
    int2*  pbuck   = (int2*) alloc((size_t)NN * CAP * 8);
    int*   obuck   = (int*)  alloc((size_t)NN * CAP * 4);
    float* din_arr = (float*)alloc(NN * 4);
    float4* dsx4   = (float4*)alloc((size_t)NN * 16);
    float* c       = (float*)alloc(NN * 4);
    float* h1s     = (float*)alloc((size_t)NN * 11 * 4);
    float* agg2    = (float*)alloc((size_t)NN * 11 * 4);
    float* v       = (float*)alloc(256);

    hipMemsetAsync(d_ws, 0, zero_bytes, stream);

    k_scat<<<(NE + 255) / 256, 256, 0, stream>>>(src, dst, cnt_in, cnt_out, pbuck, obuck);
    k_node<<<(NN + 255) / 256, 256, 0, stream>>>(x, cnt_in, cnt_out, din_arr, dsx4);
    k_conv1c<<<(NN + 63) / 64, 256, 0, stream>>>(cnt_in, cnt_out, pbuck, obuck,
                                                 din_arr, dsx4, W1, b1, h1s, c);
    k_agg2<<<(NN + 22) / 23, 256, 0, stream>>>(cnt_in, pbuck, h1s, ef, agg2);
    k_conv2_reduce<<<(NN + NPB - 1) / NPB, 512, 0, stream>>>(agg2, W2, b2, c,
                                                             cnt_out, cnt_in, t);
    k_g<<<64, 256, 0, stream>>>(t, W3, b3, g);
    k_heads1<<<256, 256, 0, stream>>>(g, Wv1, Wa1, hv_raw, ha_raw);
    k_heads2f<<<129, 256, 0, stream>>>(hv_raw, bv1, ha_raw, ba1, Wv2, bv2, Wa2, ba2,
                                       a_acc, v, done, out);
}